// Round 7
// baseline (70.146 us; speedup 1.0000x reference)
//
#include <hip/hip_runtime.h>
#include <hip/hip_bf16.h>

typedef __attribute__((ext_vector_type(8))) short short8;
typedef __attribute__((ext_vector_type(4))) float f32x4;
typedef unsigned long long ull;

#define N1 768
#define N2 768
#define LL 128
#define NS 30

// float -> bf16 bits, round-to-nearest-even (proven rounds 1-6)
__device__ __forceinline__ unsigned short f2b(float f) {
  unsigned int u = __float_as_uint(f);
  unsigned int r = (u + 0x7fffu + ((u >> 16) & 1u)) >> 16;
  return (unsigned short)r;
}

__device__ __forceinline__ float b2f(unsigned short b) {
  return __uint_as_float(((unsigned int)b) << 16);
}

// ---------------------------------------------------------------------------
// prep: block 0: S = A@A^T as bf16 table (stride 32) + Sdiag (f32).
//       blocks 1..32: w = sigmoid(W) (f32 for norm + bf16 for main).
// ---------------------------------------------------------------------------
__global__ void prep_kernel(const float* __restrict__ A, const float* __restrict__ w_vec,
                            float* __restrict__ wf, unsigned short* __restrict__ wb,
                            float* __restrict__ Sdiag, unsigned short* __restrict__ Sbg) {
  int b = blockIdx.x, t = threadIdx.x;
  if (b == 0) {
    for (int idx = t; idx < NS * NS; idx += 256) {
      int i = idx / NS, j = idx - i * NS;
      float acc = 0.f;
#pragma unroll
      for (int k = 0; k < 16; ++k) acc += A[i * 16 + k] * A[j * 16 + k];
      Sbg[i * 32 + j] = f2b(acc);
      if (i == j) Sdiag[i] = acc;
    }
  } else {
    int base = (b - 1) * 512;
#pragma unroll
    for (int k = 0; k < 2; ++k) {
      int idx = base + k * 256 + t;
      int l = idx >> 7, mm = idx & (LL - 1);
      float sig;
      if (l == mm) {
        sig = 0.5f;
      } else {
        int hi = l > mm ? l : mm, lo = l > mm ? mm : l;
        sig = 1.f / (1.f + expf(-w_vec[hi * (hi - 1) / 2 + lo]));
      }
      wf[idx] = sig;
      wb[idx] = f2b(sig);
    }
  }
}

// ---------------------------------------------------------------------------
// norm: one block per row (0..767 -> inv1 with a^2, 768..1535 -> inv2)
// ---------------------------------------------------------------------------
__global__ void norm_kernel(const int* __restrict__ X1, const int* __restrict__ X2,
                            const float* __restrict__ Sdiag, const float* __restrict__ wf,
                            float* __restrict__ inv1, float* __restrict__ inv2,
                            const float* __restrict__ a_ptr) {
  __shared__ __align__(16) float d[LL];
  __shared__ float wsum[2];
  int row = blockIdx.x, t = threadIdx.x;
  const int* X = (row < N1) ? (X1 + row * LL) : (X2 + (row - N1) * LL);
  float dv = Sdiag[X[t]];
  d[t] = dv;
  __syncthreads();
  const float4* w4 = reinterpret_cast<const float4*>(wf + t * LL);
  const float4* d4 = reinterpret_cast<const float4*>(d);
  float s = 0.f;
#pragma unroll
  for (int q = 0; q < LL / 4; ++q) {
    float4 wv = w4[q];
    float4 dd = d4[q];
    s += wv.x * dd.x + wv.y * dd.y + wv.z * dd.z + wv.w * dd.w;
  }
  s *= dv;
#pragma unroll
  for (int off = 1; off < 64; off <<= 1) s += __shfl_xor(s, off);
  if ((t & 63) == 0) wsum[t >> 6] = s;
  __syncthreads();
  if (t == 0) {
    float k = wsum[0] + wsum[1];
    if (row < N1) inv1[row] = a_ptr[0] * a_ptr[0] / sqrtf(k);
    else inv2[row - N1] = 1.f / sqrtf(k);
  }
}

// ---------------------------------------------------------------------------
// main: one block = 16x16 output tile, 512 threads (8 waves), 74 KB LDS
//   -> 2 blocks/CU.
//  phase2: direct gather V-build. Thread owns pair p2=t&255, l-half h2=t>>8:
//    8 octets x { 8 ds_read_u16 from bf16 S-table (30x32), pack, one b128
//    swizzled sV write }. No MFMA, no split tables.
//  phase3: E^T = W @ V^T with 2-way l-split: lg=wave&1 owns 64 W-rows in
//    64 VGPRs (loaded after phase2), ph=wave>>1 owns 4 p-tiles. Folded
//    epilogue, shfl(16,32) reduce, cross-lg sum via red[2][256].
// ---------------------------------------------------------------------------
__global__ __launch_bounds__(512, 4) void main_kernel(
    const int* __restrict__ X1, const int* __restrict__ X2,
    const unsigned short* __restrict__ wbg, const unsigned short* __restrict__ Sbg,
    const float* __restrict__ inv1, const float* __restrict__ inv2,
    float* __restrict__ out) {
  __shared__ __align__(16) unsigned short sV[256 * LL];  // 64 KB, swizzled
  __shared__ __align__(16) unsigned short sSb[960];      // 1920 B bf16 S-table
  __shared__ __align__(16) unsigned char x1B[16 * 144];  // bytes [row][l]
  __shared__ __align__(16) unsigned char x2B[16 * 144];
  __shared__ __align__(16) float red[2 * 256];           // cross-lg partials

  const int t = threadIdx.x;
  const int lane = t & 63, wave = t >> 6;
  const int m = lane & 15, kg = lane >> 4;
  const int i0 = blockIdx.y * 16, j0 = blockIdx.x * 16;
  char* sVb = reinterpret_cast<char*>(sV);

  // ---- per-output normalization scalars ----
  float iv1v = 0.f, iv2v = 0.f;
  if (t < 256) {
    iv1v = inv1[i0 + (t >> 4)];
    iv2v = inv2[j0 + (t & 15)];
  }

  // ---- stage bf16 S-table (1920 B = 120 uint4) ----
  if (t < 120) reinterpret_cast<uint4*>(sSb)[t] = reinterpret_cast<const uint4*>(Sbg)[t];

  // ---- stage X rows as bytes [row][l], stride 144 (16-aligned) ----
  if (t < 256) {
    int row = t >> 4, seg = t & 15;
    const int4* p1 = reinterpret_cast<const int4*>(X1 + (i0 + row) * LL + seg * 8);
    int4 a0 = p1[0], a1 = p1[1];
    ull v = 0;
    v |= (ull)(a0.x & 0xff);
    v |= (ull)(a0.y & 0xff) << 8;
    v |= (ull)(a0.z & 0xff) << 16;
    v |= (ull)(a0.w & 0xff) << 24;
    v |= (ull)(a1.x & 0xff) << 32;
    v |= (ull)(a1.y & 0xff) << 40;
    v |= (ull)(a1.z & 0xff) << 48;
    v |= (ull)(a1.w & 0xff) << 56;
    *reinterpret_cast<ull*>(x1B + row * 144 + seg * 8) = v;
    const int4* p2p = reinterpret_cast<const int4*>(X2 + (j0 + row) * LL + seg * 8);
    int4 b0 = p2p[0], b1 = p2p[1];
    ull u = 0;
    u |= (ull)(b0.x & 0xff);
    u |= (ull)(b0.y & 0xff) << 8;
    u |= (ull)(b0.z & 0xff) << 16;
    u |= (ull)(b0.w & 0xff) << 24;
    u |= (ull)(b1.x & 0xff) << 32;
    u |= (ull)(b1.y & 0xff) << 40;
    u |= (ull)(b1.z & 0xff) << 48;
    u |= (ull)(b1.w & 0xff) << 56;
    *reinterpret_cast<ull*>(x2B + row * 144 + seg * 8) = u;
  }
  __syncthreads();

  // ---- phase 2: gather V-build. thread owns pair p2, l-half h2 ----
  {
    const int p2 = t & 255;
    const int h2 = t >> 8;
    const char* a1p = reinterpret_cast<const char*>(x1B) + (p2 >> 4) * 144 + 64 * h2;
    const char* a2p = reinterpret_cast<const char*>(x2B) + (p2 & 15) * 144 + 64 * h2;
    ulonglong2 qa0 = *reinterpret_cast<const ulonglong2*>(a1p);
    ulonglong2 qa1 = *reinterpret_cast<const ulonglong2*>(a1p + 16);
    ulonglong2 qa2 = *reinterpret_cast<const ulonglong2*>(a1p + 32);
    ulonglong2 qa3 = *reinterpret_cast<const ulonglong2*>(a1p + 48);
    ulonglong2 qb0 = *reinterpret_cast<const ulonglong2*>(a2p);
    ulonglong2 qb1 = *reinterpret_cast<const ulonglong2*>(a2p + 16);
    ulonglong2 qb2 = *reinterpret_cast<const ulonglong2*>(a2p + 32);
    ulonglong2 qb3 = *reinterpret_cast<const ulonglong2*>(a2p + 48);
    const int swz = (p2 & 7) << 4;
    char* wbase = sVb + p2 * 256;
#define OCT(o, Q1, Q2)                                                                     \
    {                                                                                      \
      ull q1 = (Q1), q2 = (Q2);                                                            \
      unsigned g0 = sSb[(((unsigned)(q1) & 31u) << 5) | ((unsigned)(q2) & 31u)];           \
      unsigned g1 = sSb[(((unsigned)(q1 >> 8) & 31u) << 5) | ((unsigned)(q2 >> 8) & 31u)]; \
      unsigned g2 = sSb[(((unsigned)(q1 >> 16) & 31u) << 5) | ((unsigned)(q2 >> 16) & 31u)]; \
      unsigned g3 = sSb[(((unsigned)(q1 >> 24) & 31u) << 5) | ((unsigned)(q2 >> 24) & 31u)]; \
      unsigned g4 = sSb[(((unsigned)(q1 >> 32) & 31u) << 5) | ((unsigned)(q2 >> 32) & 31u)]; \
      unsigned g5 = sSb[(((unsigned)(q1 >> 40) & 31u) << 5) | ((unsigned)(q2 >> 40) & 31u)]; \
      unsigned g6 = sSb[(((unsigned)(q1 >> 48) & 31u) << 5) | ((unsigned)(q2 >> 48) & 31u)]; \
      unsigned g7 = sSb[(((unsigned)(q1 >> 56) & 31u) << 5) | ((unsigned)(q2 >> 56) & 31u)]; \
      uint4 pk;                                                                            \
      pk.x = g0 | (g1 << 16);                                                              \
      pk.y = g2 | (g3 << 16);                                                              \
      pk.z = g4 | (g5 << 16);                                                              \
      pk.w = g6 | (g7 << 16);                                                              \
      *reinterpret_cast<uint4*>(wbase + ((128 * h2 + 16 * (o)) ^ swz)) = pk;               \
    }
    OCT(0, qa0.x, qb0.x)
    OCT(1, qa0.y, qb0.y)
    OCT(2, qa1.x, qb1.x)
    OCT(3, qa1.y, qb1.y)
    OCT(4, qa2.x, qb2.x)
    OCT(5, qa2.y, qb2.y)
    OCT(6, qa3.x, qb3.x)
    OCT(7, qa3.y, qb3.y)
#undef OCT
  }

  // ---- W slice into registers (issued before barrier; used after) ----
  const int lg = wave & 1, ph = wave >> 1;
  short8 wreg[4][4];
  {
    const char* wby = reinterpret_cast<const char*>(wbg);
#pragma unroll
    for (int lt = 0; lt < 4; ++lt)
#pragma unroll
      for (int kk = 0; kk < 4; ++kk)
        wreg[lt][kk] = *reinterpret_cast<const short8*>(
            wby + (lg * 64 + lt * 16 + m) * 256 + kk * 64 + kg * 16);
  }
  __syncthreads();

  // ---- phase 3: E^T slice = W[lg's 64 rows] @ V^T, folded epilogue ----
#pragma unroll
  for (int pt = 0; pt < 4; ++pt) {
    const int p = ph * 64 + pt * 16 + m;
    const int sw = (p & 7) << 4;
    const char* base = sVb + p * 256;
    short8 bv[4];
#pragma unroll
    for (int kk = 0; kk < 4; ++kk)
      bv[kk] = *reinterpret_cast<const short8*>(base + ((kk * 64 + kg * 16) ^ sw));
    f32x4 c0 = {0.f, 0.f, 0.f, 0.f}, c1 = {0.f, 0.f, 0.f, 0.f};
    f32x4 c2 = {0.f, 0.f, 0.f, 0.f}, c3 = {0.f, 0.f, 0.f, 0.f};
#pragma unroll
    for (int kk = 0; kk < 4; ++kk) {
      c0 = __builtin_amdgcn_mfma_f32_16x16x32_bf16(wreg[0][kk], bv[kk], c0, 0, 0, 0);
      c1 = __builtin_amdgcn_mfma_f32_16x16x32_bf16(wreg[1][kk], bv[kk], c1, 0, 0, 0);
      c2 = __builtin_amdgcn_mfma_f32_16x16x32_bf16(wreg[2][kk], bv[kk], c2, 0, 0, 0);
      c3 = __builtin_amdgcn_mfma_f32_16x16x32_bf16(wreg[3][kk], bv[kk], c3, 0, 0, 0);
    }
    float kp = 0.f;
    {
      uint2 vv = *reinterpret_cast<const uint2*>(base + ((128 * lg + 0 + 8 * kg) ^ sw));
      kp += c0[0] * __uint_as_float(vv.x << 16) + c0[1] * __uint_as_float(vv.x & 0xffff0000u) +
            c0[2] * __uint_as_float(vv.y << 16) + c0[3] * __uint_as_float(vv.y & 0xffff0000u);
    }
    {
      uint2 vv = *reinterpret_cast<const uint2*>(base + ((128 * lg + 32 + 8 * kg) ^ sw));
      kp += c1[0] * __uint_as_float(vv.x << 16) + c1[1] * __uint_as_float(vv.x & 0xffff0000u) +
            c1[2] * __uint_as_float(vv.y << 16) + c1[3] * __uint_as_float(vv.y & 0xffff0000u);
    }
    {
      uint2 vv = *reinterpret_cast<const uint2*>(base + ((128 * lg + 64 + 8 * kg) ^ sw));
      kp += c2[0] * __uint_as_float(vv.x << 16) + c2[1] * __uint_as_float(vv.x & 0xffff0000u) +
            c2[2] * __uint_as_float(vv.y << 16) + c2[3] * __uint_as_float(vv.y & 0xffff0000u);
    }
    {
      uint2 vv = *reinterpret_cast<const uint2*>(base + ((128 * lg + 96 + 8 * kg) ^ sw));
      kp += c3[0] * __uint_as_float(vv.x << 16) + c3[1] * __uint_as_float(vv.x & 0xffff0000u) +
            c3[2] * __uint_as_float(vv.y << 16) + c3[3] * __uint_as_float(vv.y & 0xffff0000u);
    }
    kp += __shfl_xor(kp, 16);
    kp += __shfl_xor(kp, 32);
    if (kg == 0) red[lg * 256 + p] = kp;
  }
  __syncthreads();

  // ---- final: cross-lg sum, fused normalization, store ----
  if (t < 256) {
    float s = red[t] + red[256 + t];
    out[(i0 + (t >> 4)) * N2 + j0 + (t & 15)] = s * iv1v * iv2v;
  }
}

// ---------------------------------------------------------------------------
extern "C" void kernel_launch(void* const* d_in, const int* in_sizes, int n_in,
                              void* d_out, int out_size, void* d_ws, size_t ws_size,
                              hipStream_t stream) {
  const int* X1 = (const int*)d_in[0];
  const int* X2 = (const int*)d_in[1];
  const float* a = (const float*)d_in[2];
  const float* A = (const float*)d_in[3];
  const float* w_vec = (const float*)d_in[4];
  float* out = (float*)d_out;

  char* ws = (char*)d_ws;
  float* wf = (float*)(ws + 0);                        // 64 KB
  unsigned short* wb = (unsigned short*)(ws + 65536);  // 32 KB
  float* Sdiag = (float*)(ws + 98304);                 // 128 B
  unsigned short* Sbg = (unsigned short*)(ws + 98432); // 1920 B
  float* inv1 = (float*)(ws + 100352);                 // 3 KB
  float* inv2 = (float*)(ws + 103424);                 // 3 KB

  prep_kernel<<<33, 256, 0, stream>>>(A, w_vec, wf, wb, Sdiag, Sbg);
  norm_kernel<<<N1 + N2, 128, 0, stream>>>(X1, X2, Sdiag, wf, inv1, inv2, a);
  main_kernel<<<dim3(N2 / 16, N1 / 16), 512, 0, stream>>>(X1, X2, wb, Sbg, inv1, inv2, out);
}